// Round 6
// baseline (128.962 us; speedup 1.0000x reference)
//
#include <hip/hip_runtime.h>

typedef _Float16 f16x2 __attribute__((ext_vector_type(2)));
typedef __fp16  fp16x2 __attribute__((ext_vector_type(2)));

// Problem constants
constexpr int NKW  = 25, NK = 625;
constexpr int WPADR = 132;                  // reference padded width
constexpr int WPT   = 160;                  // padded halves per (ki,kj) weight row
constexpr int RST   = 35;                   // LDS row stride in uint2 (+1 anti-conflict)
constexpr int BROWS = 30;                   // rows per band (5 ki * 5 + 5 halo)
constexpr int BITEM = BROWS * 32;           // 960 float4 items per band
constexpr int NBAND = 5;                    // 5 bands x 125 outputs = 625

union U2H { unsigned int u; f16x2 h; fp16x2 p; };

// ---- gather: dense W -> f16 weights, zero-padded 16-slot rows, TRANSPOSED ----
// wgpT as uint4[20][625]; slot j of output k holds padded halves 8j..8j+7.
// Real data at in-row slot o..o+9, o = (5*kj+2) & 3. (verified earlier rounds)
__global__ void gather_wp(const float* __restrict__ W, _Float16* __restrict__ wgpT) {
    int t = blockIdx.x * 256 + threadIdx.x;
    if (t >= NK * WPT) return;
    int k = t / WPT, p = t % WPT;
    int di = p >> 4, s = p & 15;
    int ki = k / NKW, kj = k % NKW;
    int o = (5 * kj + 2) & 3;
    int j = s - o;
    float val = 0.f;
    if (j >= 0 && j < 10)
        val = W[(size_t)((ki * 5 + di) * WPADR + kj * 5 + j) * NK + k];
    wgpT[((size_t)(p >> 3) * NK + k) * 8 + (p & 7)] = (_Float16)val;
}

__device__ __forceinline__ float dot2acc(unsigned int a, unsigned int b, float c) {
    U2H ua, ub; ua.u = a; ub.u = b;
#if __has_builtin(__builtin_amdgcn_fdot2)
    return __builtin_amdgcn_fdot2(ua.h, ub.h, c, false);
#else
    return c + (float)ua.h.x * (float)ub.h.x + (float)ua.h.y * (float)ub.h.y;
#endif
}

// R19: OVERSUBSCRIBED SHATTER. Four structural nulls (R15-R18: serial /
// split-barrier / de-capped / band-pipelined all 126.6-127.9) share ONE
// invariant: grid == resident capacity (1024 blocks on 1024 slots). All
// blocks per CU start together and stall on the same phase together — R1's
// measured counters for this family (VALUBusy 8.9%, HBM 12%, Occ 25%) are
// the lockstep-latency signature. Fix: 5120 SHORT blocks (one (img,band)
// job: stage 30 rows into 8.4KB LDS, 1 barrier, 125 outputs, exit). 20
// blocks/CU assigned vs ~6 resident -> scheduler backfills continuously;
// staggered starts give cross-block stage||compute overlap with zero
// hand-built pipelining. Compute/indexing byte-identical to R18 (verified).
template <bool USE_WG>
__global__ __launch_bounds__(256)
void lc2d_shard(const float* __restrict__ x, const _Float16* __restrict__ wgpT,
                const float* __restrict__ Wfull,
                const float* __restrict__ bias, float* __restrict__ out) {
    __shared__ uint2 xs[BROWS * RST];       // 8400 B, single buffer

    const int blk  = blockIdx.x;            // 0..5119
    const int b    = blk / NBAND;           // image
    const int t    = blk - b * NBAND;       // band 0..4
    const int tid  = threadIdx.x;
    const int lane = tid & 63;
    const int pairidx = (tid >> 6) * 32 + (lane & 31);   // 0..127
    const int half = lane >> 5;             // lane pair (l, l^32) shares pairidx
    const int di0  = half * 5;              // this thread's 5 di rows
    const bool active = pairidx < 125;      // 125 outputs per band
    const int ki_l = pairidx / 25;          // 0..4 within band
    const int kj   = pairidx - ki_l * 25;
    const float* xb = x + ((size_t)b << 14);

    // ---- stage band rows (unpadded 25t-2 .. 25t+27) as f16 into LDS ----
    // 960 float4 items, 3.75/thread; issue all loads first (in flight), then
    // boundary zeros + weight loads overlap the HBM latency, then write.
    float4 tmp[4];
    {
        const int r0 = 25 * t - 2;
#pragma unroll
        for (int u = 0; u < 4; ++u) {
            const int i = tid + u * 256;
            tmp[u] = make_float4(0.f, 0.f, 0.f, 0.f);
            if (i < BITEM) {
                const int r = r0 + (i >> 5), q = i & 31;
                if (r >= 0 && r < 128)
                    tmp[u] = *reinterpret_cast<const float4*>(xb + (r << 7) + (q << 2));
            }
        }
    }

    // boundary zeros: slots q=0 and q=33 of all 30 rows (60 uint2)
    for (int i = tid; i < 2 * BROWS; i += 256)
        xs[(i >> 1) * RST + (i & 1) * 33] = make_uint2(0u, 0u);

    // ---- weights for this band: coalesced uint4 from wgpT (or dense) ----
    uint4 wq[10];
    float bv = 0.f;
    if (active) {
        const int k = 125 * t + pairidx;    // global output index
        if constexpr (USE_WG) {
            const uint4* wt4 = reinterpret_cast<const uint4*>(wgpT);
#pragma unroll
            for (int j = 0; j < 10; ++j) wq[j] = wt4[(size_t)(half * 10 + j) * NK + k];
        } else {
            const int ki = 5 * t + ki_l;
            const int o = (5 * kj + 2) & 3;
#pragma unroll
            for (int j = 0; j < 10; ++j) {
                const int di = di0 + (j >> 1), pb = (j & 1) * 8;
                unsigned int uu[4];
#pragma unroll
                for (int m = 0; m < 4; ++m) {
                    float f0 = 0.f, f1 = 0.f;
                    const int j0 = pb + 2 * m - o, j1 = pb + 2 * m + 1 - o;
                    const size_t rowb = (size_t)((ki * 5 + di) * WPADR + kj * 5);
                    if (j0 >= 0 && j0 < 10) f0 = Wfull[(rowb + j0) * NK + k];
                    if (j1 >= 0 && j1 < 10) f1 = Wfull[(rowb + j1) * NK + k];
                    U2H u; u.p = __builtin_amdgcn_cvt_pkrtz(f0, f1);
                    uu[m] = u.u;
                }
                wq[j] = make_uint4(uu[0], uu[1], uu[2], uu[3]);
            }
        }
        if (half == 0) bv = bias[k];
    }

    // ---- LDS write of staged band, then one barrier ----
    {
#pragma unroll
        for (int u = 0; u < 4; ++u) {
            const int i = tid + u * 256;
            if (i < BITEM) {
                const int idx = i >> 5, q = (i & 31) + 1;
                U2H u0h, u1h;
                u0h.p = __builtin_amdgcn_cvt_pkrtz(tmp[u].x, tmp[u].y);
                u1h.p = __builtin_amdgcn_cvt_pkrtz(tmp[u].z, tmp[u].w);
                xs[idx * RST + q] = make_uint2(u0h.u, u1h.u);
            }
        }
    }
    __syncthreads();

    // ---- compute 125 outputs (rows 5*ki_l+di0+d, verified mapping) ----
    float acc0 = 0.f, acc1 = 0.f;
    if (active) {
        const uint2* base = xs + (5 * ki_l + di0) * RST + ((5 * kj + 2) >> 2);
#pragma unroll
        for (int d = 0; d < 5; ++d) {
            const uint2* rowp = base + d * RST;
            const uint2 a0 = rowp[0], a1 = rowp[1], a2 = rowp[2], a3 = rowp[3];
            const uint4 wA = wq[2 * d], wB = wq[2 * d + 1];
            acc0 = dot2acc(a0.x, wA.x, acc0);
            acc1 = dot2acc(a0.y, wA.y, acc1);
            acc0 = dot2acc(a1.x, wA.z, acc0);
            acc1 = dot2acc(a1.y, wA.w, acc1);
            acc0 = dot2acc(a2.x, wB.x, acc0);
            acc1 = dot2acc(a2.y, wB.y, acc1);
            acc0 = dot2acc(a3.x, wB.z, acc0);
            acc1 = dot2acc(a3.y, wB.w, acc1);
        }
    }
    float acc = acc0 + acc1;
    float other = __shfl_xor(acc, 32, 64);
    if (active && half == 0)
        out[(size_t)b * NK + 125 * t + pairidx] = acc + other + bv;
}

extern "C" void kernel_launch(void* const* d_in, const int* in_sizes, int n_in,
                              void* d_out, int out_size, void* d_ws, size_t ws_size,
                              hipStream_t stream) {
    const float* x    = (const float*)d_in[0];
    const float* W    = (const float*)d_in[1];
    const float* bias = (const float*)d_in[2];
    float* out = (float*)d_out;

    const dim3 grid(1024 * NBAND);          // 5120 short blocks: oversubscribe CUs
    if (ws_size >= (size_t)NK * WPT * sizeof(_Float16)) {
        _Float16* wgpT = (_Float16*)d_ws;
        gather_wp<<<(NK * WPT + 255) / 256, 256, 0, stream>>>(W, wgpT);
        lc2d_shard<true><<<grid, 256, 0, stream>>>(x, wgpT, W, bias, out);
    } else {
        lc2d_shard<false><<<grid, 256, 0, stream>>>(x, nullptr, W, bias, out);
    }
}

// Round 7
// 122.048 us; speedup vs baseline: 1.0567x; 1.0567x over previous
//
#include <hip/hip_runtime.h>

typedef _Float16 f16x2 __attribute__((ext_vector_type(2)));
typedef __fp16  fp16x2 __attribute__((ext_vector_type(2)));

// Problem constants
constexpr int NKW  = 25, NK = 625;
constexpr int WPADR = 132;                  // reference padded width
constexpr int WPT   = 160;                  // padded halves per (ki,kj) weight row
constexpr int RST   = 35;                   // LDS row stride in uint2 (+1 anti-conflict)
constexpr int IMG   = 8;                    // images per block (weight reuse factor)
constexpr int NSLAB = 6;                    // ki slabs: NKI = {5,4,4,4,4,4}
constexpr int MAXR  = 30;                   // max staged rows (slab 0)

union U2H { unsigned int u; f16x2 h; fp16x2 p; };

// ---- gather: dense W -> f16 weights, zero-padded 16-slot rows, TRANSPOSED ----
// wgpT as uint4[20][625]; slot j of output k holds padded halves 8j..8j+7.
// Real data at in-row slot o..o+9, o = (5*kj+2) & 3, matching aligned LDS
// window h0 = (5*kj+2) & ~3.
__global__ void gather_wp(const float* __restrict__ W, _Float16* __restrict__ wgpT) {
    int t = blockIdx.x * 256 + threadIdx.x;
    if (t >= NK * WPT) return;
    int k = t / WPT, p = t % WPT;
    int di = p >> 4, s = p & 15;
    int ki = k / NKW, kj = k % NKW;
    int o = (5 * kj + 2) & 3;
    int j = s - o;
    float val = 0.f;
    if (j >= 0 && j < 10)
        val = W[(size_t)((ki * 5 + di) * WPADR + kj * 5 + j) * NK + k];
    wgpT[((size_t)(p >> 3) * NK + k) * 8 + (p & 7)] = (_Float16)val;
}

__device__ __forceinline__ float dot2acc(unsigned int a, unsigned int b, float c) {
    U2H ua, ub; ua.u = a; ub.u = b;
#if __has_builtin(__builtin_amdgcn_fdot2)
    return __builtin_amdgcn_fdot2(ua.h, ub.h, c, false);
#else
    return c + (float)ua.h.x * (float)ub.h.x + (float)ua.h.y * (float)ub.h.y;
#endif
}

// R20: CHAMPION RESTORATION. R15-R19 (five structurally different
// one-image/band/shard schedules) were all 5-8us WORSE than this R0 kernel
// (121.4) and mutually within noise -> surviving theory: the harness's two
// 256-MiB poison fills (41us @ 6.5TB/s each) saturate HBM around/while our
// kernels run; kernel schedule is irrelevant under that contention, and the
// champion's only real edge is 8x weight reuse (31MB vs 210MB of wgpT
// traffic). Restored byte-for-byte except ONE delta: the block prologue
// issues image-0's x loads BEFORE the 10 weight loads (x HBM latency now
// covers the weight fetch; previously weights went first).
template <bool USE_WG>
__global__ __launch_bounds__(256, 4)
void lc2d_pipe(const float* __restrict__ x, const _Float16* __restrict__ wgpT,
               const float* __restrict__ Wfull,
               const float* __restrict__ bias, float* __restrict__ out) {
    __shared__ uint2 xs[2][MAXR * RST];     // 16800 B

    // swizzle: flat -> (grp, slab) with grp % 8 == flat % 8 (XCD-pinned)
    const int flat = blockIdx.x;            // 0..767
    const int xcd  = flat & 7;
    const int j_   = flat >> 3;             // 0..95
    const int grp  = xcd + 8 * (j_ & 15);   // 0..127
    const int slab = j_ >> 4;               // 0..5
    const int K0   = slab ? (4 * slab + 1) : 0;   // 0,5,9,13,17,21
    const int NKI  = slab ? 4 : 5;
    const int R    = 5 * NKI + 5;           // staged rows: 30 / 25
    const int NOUT = NKI * NKW;             // 125 / 100
    const int row0 = 5 * K0 - 2;            // unpadded row of staged idx 0
    const int tid  = threadIdx.x;
    const int b0   = grp * IMG;

    // pair mapping: wave w, lane l -> pair = w*32 + (l&31), half = (l>>5)&1
    const int lane = tid & 63;
    const int pairidx = (tid >> 6) * 32 + (lane & 31);
    const int half = (lane >> 5) & 1;
    const bool active = pairidx < NOUT;
    const int ki_l = pairidx / 25;
    const int kj   = pairidx - ki_l * 25;
    const int k    = (K0 + ki_l) * NKW + kj;
    const int di0  = half * 5;              // this thread's 5 di rows

    // ---- pipeline phases ----
    auto stage_load = [&](int img, float4* tmp) {
        const float* xb = x + ((size_t)(b0 + img) << 14);
#pragma unroll
        for (int t = 0; t < 4; ++t) {
            const int i = tid + t * 256;
            tmp[t] = make_float4(0.f, 0.f, 0.f, 0.f);
            if (i < R * 32) {
                const int idx = i >> 5, q = i & 31;
                const int r = row0 + idx;
                if (r >= 0 && r < 128)
                    tmp[t] = *reinterpret_cast<const float4*>(xb + (r << 7) + (q << 2));
            }
        }
    };
    auto stage_write = [&](int buf, const float4* tmp) {
#pragma unroll
        for (int t = 0; t < 4; ++t) {
            const int i = tid + t * 256;
            if (i < R * 32) {
                const int idx = i >> 5, q = (i & 31) + 1;
                U2H u0, u1;
                u0.p = __builtin_amdgcn_cvt_pkrtz(tmp[t].x, tmp[t].y);
                u1.p = __builtin_amdgcn_cvt_pkrtz(tmp[t].z, tmp[t].w);
                xs[buf][idx * RST + q] = make_uint2(u0.u, u1.u);
            }
        }
    };

    // ---- prologue, reordered: issue image-0 x loads FIRST (HBM latency
    // covers the weight fetch below), then weights, then LDS writes ----
    float4 tmpA[4], tmpB[4];
    stage_load(0, tmpA);                    // x HBM loads in flight

    uint4 wq[10];
    float bval = 0.f;
    if (active) {
        if (USE_WG) {
            const uint4* wt4 = reinterpret_cast<const uint4*>(wgpT);
#pragma unroll
            for (int j = 0; j < 10; ++j) wq[j] = wt4[(size_t)(half * 10 + j) * NK + k];
        } else {
            const int o = (5 * kj + 2) & 3;
#pragma unroll
            for (int j = 0; j < 10; ++j) {
                const int di = di0 + (j >> 1), pb = (j & 1) * 8;
                unsigned int uu[4];
#pragma unroll
                for (int m = 0; m < 4; ++m) {
                    float f0 = 0.f, f1 = 0.f;
                    const int j0 = pb + 2 * m - o, j1 = pb + 2 * m + 1 - o;
                    const size_t rowb = (size_t)(((K0 + ki_l) * 5 + di) * WPADR + kj * 5);
                    if (j0 >= 0 && j0 < 10) f0 = Wfull[(rowb + j0) * NK + k];
                    if (j1 >= 0 && j1 < 10) f1 = Wfull[(rowb + j1) * NK + k];
                    U2H u; u.p = __builtin_amdgcn_cvt_pkrtz(f0, f1);
                    uu[m] = u.u;
                }
                wq[j] = make_uint4(uu[0], uu[1], uu[2], uu[3]);
            }
        }
        if (half == 0) bval = bias[k];
    }

    // ---- boundary zeros, once, both buffers (q=0 left pad, q=33 right pad) ----
    for (int i = tid; i < 4 * R; i += 256)
        xs[i & 1][(i >> 2) * RST + ((i >> 1) & 1) * 33] = make_uint2(0u, 0u);

    stage_write(0, tmpA);                   // waits only tmpA's loads
    stage_load(1, tmpB);
    __syncthreads();

    for (int i = 0; i < IMG; ++i) {
        // issue image i+2's loads into the tmp slot just freed (image i's)
        if (i + 2 < IMG) stage_load(i + 2, (i & 1) ? tmpB : tmpA);

        float acc0 = 0.f, acc1 = 0.f;
        if (active) {
            const uint2* base = xs[i & 1] + (5 * ki_l + di0) * RST + ((5 * kj + 2) >> 2);
#pragma unroll
            for (int d = 0; d < 5; ++d) {
                const uint2* rowp = base + d * RST;
                const uint2 a0 = rowp[0], a1 = rowp[1], a2 = rowp[2], a3 = rowp[3];
                const uint4 wA = wq[2 * d], wB = wq[2 * d + 1];
                acc0 = dot2acc(a0.x, wA.x, acc0);
                acc1 = dot2acc(a0.y, wA.y, acc1);
                acc0 = dot2acc(a1.x, wA.z, acc0);
                acc1 = dot2acc(a1.y, wA.w, acc1);
                acc0 = dot2acc(a2.x, wB.x, acc0);
                acc1 = dot2acc(a2.y, wB.y, acc1);
                acc0 = dot2acc(a3.x, wB.z, acc0);
                acc1 = dot2acc(a3.y, wB.w, acc1);
            }
        }
        // combine lane pair (l, l^32) within the wave; half 0 stores
        float acc = acc0 + acc1;
        float other = __shfl_xor(acc, 32, 64);
        if (active && half == 0)
            out[(size_t)(b0 + i) * NK + k] = acc + other + bval;

        // write image i+1 into the other LDS buffer; waits only its own loads
        if (i + 1 < IMG) stage_write((i + 1) & 1, (i & 1) ? tmpA : tmpB);
        __syncthreads();
    }
}

extern "C" void kernel_launch(void* const* d_in, const int* in_sizes, int n_in,
                              void* d_out, int out_size, void* d_ws, size_t ws_size,
                              hipStream_t stream) {
    const float* x    = (const float*)d_in[0];
    const float* W    = (const float*)d_in[1];
    const float* bias = (const float*)d_in[2];
    float* out = (float*)d_out;

    const dim3 grid(128 * NSLAB);           // 768 blocks, XCD-swizzled in-kernel
    if (ws_size >= (size_t)NK * WPT * sizeof(_Float16)) {
        _Float16* wgpT = (_Float16*)d_ws;
        gather_wp<<<(NK * WPT + 255) / 256, 256, 0, stream>>>(W, wgpT);
        lc2d_pipe<true><<<grid, 256, 0, stream>>>(x, wgpT, W, bias, out);
    } else {
        lc2d_pipe<false><<<grid, 256, 0, stream>>>(x, nullptr, W, bias, out);
    }
}